// Round 11
// baseline (468.914 us; speedup 1.0000x reference)
//
#include <hip/hip_runtime.h>

#define NN 100000
#define NE 1600000
#define DF 128
#define NH (NN * DF)
#define EPS 1e-5f
#define NB 196        // buckets of 512 dst nodes
#define CAP 10240     // per-bucket edge capacity
#define EPB 8192      // edges per k_part block
#define GB 2048       // gather blocks: 8 blocks/CU x 256 CU -> 8192 waves (full)

typedef unsigned int uint;
typedef unsigned short ushort;
typedef __attribute__((ext_vector_type(8))) short bf16x8;
typedef __attribute__((ext_vector_type(4))) float f32x4;

__device__ __forceinline__ ushort f2bf(float f) {
    uint u = __float_as_uint(f);
    u += 0x7fffu + ((u >> 16) & 1u);
    return (ushort)(u >> 16);
}
__device__ __forceinline__ float bflo(uint u) { return __uint_as_float(u << 16); }
__device__ __forceinline__ float bfhi(uint u) { return __uint_as_float(u & 0xffff0000u); }

// ---- pass B: partition edges into 196 bucket lists, packed (src | dloc<<17) ----
__launch_bounds__(256)
__global__ void k_part(const int* __restrict__ src, const int* __restrict__ dst,
                       int* __restrict__ gcur, uint* __restrict__ ebuf) {
    __shared__ int cnt[NB], base[NB];
    int t = threadIdx.x;
    if (t < NB) cnt[t] = 0;
    __syncthreads();
    int e0 = blockIdx.x * EPB;
#pragma unroll
    for (int i = 0; i < EPB / 256; ++i) {
        int e = e0 + i * 256 + t;
        if (e < NE) atomicAdd(&cnt[dst[e] >> 9], 1);
    }
    __syncthreads();
    if (t < NB) {
        base[t] = atomicAdd(&gcur[t], cnt[t]);
        cnt[t] = 0;
    }
    __syncthreads();
#pragma unroll
    for (int i = 0; i < EPB / 256; ++i) {
        int e = e0 + i * 256 + t;
        if (e < NE) {
            int d = dst[e];
            int b = d >> 9;
            int off = atomicAdd(&cnt[b], 1);
            ebuf[b * CAP + base[b] + off] = (uint)src[e] | ((uint)(d & 511) << 17);
        }
    }
}

// ---- pass C1: per bucket, per-node degree -> dis/di/rp (bucket prefix in-block) ----
__launch_bounds__(256)
__global__ void k_c1(const uint* __restrict__ ebuf, const int* __restrict__ gcur,
                     float* __restrict__ dis, float* __restrict__ di,
                     int* __restrict__ rp) {
    __shared__ int ncnt[512];
    __shared__ int ssum[256];
    __shared__ int bsh[256];
    __shared__ int sbase;
    int b = blockIdx.x, t = threadIdx.x;
    bsh[t] = (t < b && t < NB) ? gcur[t] : 0;
    ncnt[t] = 0;
    ncnt[t + 256] = 0;
    __syncthreads();
    for (int off = 128; off; off >>= 1) {
        if (t < off) bsh[t] += bsh[t + off];
        __syncthreads();
    }
    if (t == 0) sbase = bsh[0];
    __syncthreads();
    int base = sbase;

    int ne = gcur[b];
    const uint* eb = ebuf + (size_t)b * CAP;
    for (int e = t; e < ne; e += 256) atomicAdd(&ncnt[eb[e] >> 17], 1);
    __syncthreads();
    int a0 = ncnt[t * 2], a1 = ncnt[t * 2 + 1];
    int ps = a0 + a1;
    ssum[t] = ps;
    __syncthreads();
    for (int off = 1; off < 256; off <<= 1) {
        int x = (t >= off) ? ssum[t - off] : 0;
        __syncthreads();
        ssum[t] += x;
        __syncthreads();
    }
    int excl = ssum[t] - ps;
    int g0 = b * 512 + t * 2;
    if (g0 < NN) {
        rp[g0] = base + excl;
        float d = (float)a0 + 1.0f;
        dis[g0] = rsqrtf(d);
        di[g0] = 1.0f / d;
    }
    if (g0 + 1 < NN) {
        rp[g0 + 1] = base + excl + a0;
        float d = (float)a1 + 1.0f;
        dis[g0 + 1] = rsqrtf(d);
        di[g0 + 1] = 1.0f / d;
    }
    if (b == NB - 1 && t == 0) rp[NN] = NE;
}

// ---- pass C2: per bucket, place (src, coef) into CSR window (L2-combined) ----
__launch_bounds__(256)
__global__ void k_c2(const uint* __restrict__ ebuf, const int* __restrict__ gcur,
                     const int* __restrict__ rp, const float* __restrict__ dis,
                     uint2* __restrict__ ec) {
    __shared__ int cur[512];
    __shared__ float dl[512];
    int b = blockIdx.x, t = threadIdx.x;
#pragma unroll
    for (int i = 0; i < 2; ++i) {
        int g = b * 512 + t + i * 256;
        if (g < NN) {
            cur[t + i * 256] = rp[g];
            dl[t + i * 256] = dis[g];
        }
    }
    __syncthreads();
    int ne = gcur[b];
    const uint* eb = ebuf + (size_t)b * CAP;
    for (int e = t; e < ne; e += 256) {
        uint u = eb[e];
        int s = u & 0x1FFFF;
        int dloc = u >> 17;
        int pos = atomicAdd(&cur[dloc], 1);
        ec[pos] = make_uint2((uint)s, __float_as_uint(dis[s] * dl[dloc]));
    }
}

// ---- convert W -> bf16 transposed+swizzled ----
__global__ void k_cvt_w(const float* __restrict__ W, ushort* __restrict__ Wt) {
    int id = blockIdx.x * blockDim.x + threadIdx.x;
    int n = id & 127, k = id >> 7;
    ushort b = f2bf(W[id]);
    int byte = n * 256 + (((k >> 3) ^ (n & 7)) << 4) + ((k & 7) << 1);
    *(ushort*)((char*)Wt + byte) = b;
}

// ---- MFMA matmul; MODE 0: bf16 A, 1: bf16 A + BN/ReLU, 2: f32 A (converts) ----
template <int MODE>
__launch_bounds__(256, 2)
__global__ void k_mm_mfma(const void* __restrict__ Xv, const ushort* __restrict__ Wt,
                          const float* __restrict__ par, ushort* __restrict__ Y,
                          int nrows) {
    __shared__ uint4 ws4[2048];  // 32 KB
    char* ws = (char*)ws4;
    const int tid = threadIdx.x;
    const int wv = tid >> 6, l = tid & 63;
    const int l15 = l & 15, l4 = l >> 4;
    const int row_base = blockIdx.x * 128 + wv * 32;
    const bool act = row_base < nrows;

    bf16x8 a[2][4];
    if (act) {
#pragma unroll
        for (int mt = 0; mt < 2; ++mt)
#pragma unroll
            for (int ks = 0; ks < 4; ++ks) {
                int r = row_base + mt * 16 + l15;
                if (MODE == 2) {
                    const float* Xf = (const float*)Xv;
                    float4 f0 = *(const float4*)&Xf[(size_t)r * 128 + ks * 32 + l4 * 8];
                    float4 f1 = *(const float4*)&Xf[(size_t)r * 128 + ks * 32 + l4 * 8 + 4];
                    bf16x8 v;
                    v[0] = (short)f2bf(f0.x); v[1] = (short)f2bf(f0.y);
                    v[2] = (short)f2bf(f0.z); v[3] = (short)f2bf(f0.w);
                    v[4] = (short)f2bf(f1.x); v[5] = (short)f2bf(f1.y);
                    v[6] = (short)f2bf(f1.z); v[7] = (short)f2bf(f1.w);
                    a[mt][ks] = v;
                } else {
                    const ushort* Xb = (const ushort*)Xv;
                    a[mt][ks] = *(const bf16x8*)&Xb[(size_t)r * 128 + ks * 32 + l4 * 8];
                }
            }
        if (MODE == 1) {
#pragma unroll
            for (int ks = 0; ks < 4; ++ks) {
                int k0 = ks * 32 + l4 * 8;
                float4 sa = *(const float4*)&par[k0];
                float4 sb = *(const float4*)&par[k0 + 4];
                float4 ha = *(const float4*)&par[128 + k0];
                float4 hb = *(const float4*)&par[128 + k0 + 4];
                float sc[8] = {sa.x, sa.y, sa.z, sa.w, sb.x, sb.y, sb.z, sb.w};
                float sh[8] = {ha.x, ha.y, ha.z, ha.w, hb.x, hb.y, hb.z, hb.w};
#pragma unroll
                for (int mt = 0; mt < 2; ++mt)
#pragma unroll
                    for (int j = 0; j < 8; ++j) {
                        float f = __uint_as_float(((uint)(ushort)a[mt][ks][j]) << 16);
                        f = fmaxf(f * sc[j] + sh[j], 0.0f);
                        a[mt][ks][j] = (short)f2bf(f);
                    }
            }
        }
    }
    const uint4* Wg = (const uint4*)Wt;
#pragma unroll
    for (int i = 0; i < 8; ++i) ws4[tid + i * 256] = Wg[tid + i * 256];
    __syncthreads();
    if (!act) return;

    f32x4 acc[2][8];
#pragma unroll
    for (int mt = 0; mt < 2; ++mt)
#pragma unroll
        for (int nt = 0; nt < 8; ++nt) acc[mt][nt] = (f32x4){0.f, 0.f, 0.f, 0.f};

#pragma unroll
    for (int ks = 0; ks < 4; ++ks) {
        bf16x8 b[8];
#pragma unroll
        for (int nt = 0; nt < 8; ++nt) {
            int n = nt * 16 + l15;
            int chunk = (ks * 4 + l4) ^ (n & 7);
            b[nt] = *(const bf16x8*)(ws + n * 256 + chunk * 16);
        }
#pragma unroll
        for (int nt = 0; nt < 8; ++nt) {
            acc[0][nt] = __builtin_amdgcn_mfma_f32_16x16x32_bf16(a[0][ks], b[nt], acc[0][nt], 0, 0, 0);
            acc[1][nt] = __builtin_amdgcn_mfma_f32_16x16x32_bf16(a[1][ks], b[nt], acc[1][nt], 0, 0, 0);
        }
    }
#pragma unroll
    for (int mt = 0; mt < 2; ++mt)
#pragma unroll
        for (int nt = 0; nt < 8; ++nt)
#pragma unroll
            for (int r = 0; r < 4; ++r) {
                int ro = row_base + mt * 16 + l4 * 4 + r;
                Y[(size_t)ro * 128 + nt * 16 + l15] = f2bf(acc[mt][nt][r]);
            }
}

// ---- CSR gather (bf16) + fused BN stats; grid-stride, 8-deep unroll ----
__launch_bounds__(256, 8)
__global__ void k_gather_b(const ushort* __restrict__ H, const int* __restrict__ rp,
                           const uint2* __restrict__ ec, const float* __restrict__ di,
                           const float* __restrict__ b, uint* __restrict__ outb,
                           float* __restrict__ partial) {
    int wv = threadIdx.x >> 6, lane = threadIdx.x & 63;
    const uint* H32 = (const uint*)H;
    float2 bb = *(const float2*)&b[lane * 2];
    float s0 = 0.f, s1 = 0.f, q0 = 0.f, q1 = 0.f;

    for (int wid = blockIdx.x * 4 + wv; wid < NN; wid += GB * 4) {
        int beg = rp[wid], end = rp[wid + 1];
        float dv = di[wid];
        uint hu = H32[(size_t)wid * 64 + lane];
        float ax = bflo(hu) * dv + bb.x;
        float ay = bfhi(hu) * dv + bb.y;
        int i = beg;
        for (; i + 7 < end; i += 8) {
            uint2 e[8];
            uint u[8];
#pragma unroll
            for (int j = 0; j < 8; ++j) e[j] = ec[i + j];
#pragma unroll
            for (int j = 0; j < 8; ++j) u[j] = H32[(size_t)e[j].x * 64 + lane];
#pragma unroll
            for (int j = 0; j < 8; ++j) {
                float c = __uint_as_float(e[j].y);
                ax += bflo(u[j]) * c;
                ay += bfhi(u[j]) * c;
            }
        }
        for (; i + 3 < end; i += 4) {
            uint2 e[4];
            uint u[4];
#pragma unroll
            for (int j = 0; j < 4; ++j) e[j] = ec[i + j];
#pragma unroll
            for (int j = 0; j < 4; ++j) u[j] = H32[(size_t)e[j].x * 64 + lane];
#pragma unroll
            for (int j = 0; j < 4; ++j) {
                float c = __uint_as_float(e[j].y);
                ax += bflo(u[j]) * c;
                ay += bfhi(u[j]) * c;
            }
        }
        for (; i < end; ++i) {
            uint2 e0 = ec[i];
            uint u = H32[(size_t)e0.x * 64 + lane];
            float c = __uint_as_float(e0.y);
            ax += bflo(u) * c;
            ay += bfhi(u) * c;
        }
        outb[(size_t)wid * 64 + lane] = (uint)f2bf(ax) | ((uint)f2bf(ay) << 16);
        s0 += ax; q0 += ax * ax;
        s1 += ay; q1 += ay * ay;
    }

    __shared__ float Ls[4][128], Lq[4][128];
    Ls[wv][2 * lane] = s0;
    Ls[wv][2 * lane + 1] = s1;
    Lq[wv][2 * lane] = q0;
    Lq[wv][2 * lane + 1] = q1;
    __syncthreads();
    int t = threadIdx.x;
    if (t < 128)
        partial[(size_t)blockIdx.x * 256 + t] = Ls[0][t] + Ls[1][t] + Ls[2][t] + Ls[3][t];
    else {
        int c = t - 128;
        partial[(size_t)blockIdx.x * 256 + t] = Lq[0][c] + Lq[1][c] + Lq[2][c] + Lq[3][c];
    }
}

// ---- reduce partials + BN params (fused) ----
__global__ void k_red(const float* __restrict__ partial, const float* __restrict__ g,
                      const float* __restrict__ be, float* __restrict__ par) {
    int c = threadIdx.x;  // 0..255
    float acc = 0.f;
    for (int b = 0; b < GB; ++b) acc += partial[b * 256 + c];
    __shared__ float sh[256];
    sh[c] = acc;
    __syncthreads();
    if (c < 128) {
        float mu = sh[c] * (1.0f / NN);
        float var = sh[c + 128] * (1.0f / NN) - mu * mu;
        float inv = rsqrtf(var + EPS);
        float scv = inv * g[c];
        par[c] = scv;
        par[128 + c] = be[c] - mu * scv;
    }
}

// ---- layer-3: affine+relu on bf16 agg, dot W3; one wave per node ----
__global__ void k_mm2(const uint* __restrict__ X, const float* __restrict__ W3,
                      const float* __restrict__ par, float* __restrict__ Z) {
    int wid = (int)(((long long)blockIdx.x * blockDim.x + threadIdx.x) >> 6);
    int lane = threadIdx.x & 63;
    if (wid >= NN) return;
    uint xu = X[(size_t)wid * 64 + lane];
    float2 sc = *(const float2*)&par[2 * lane];
    float2 sh = *(const float2*)&par[128 + 2 * lane];
    float x0 = fmaxf(bflo(xu) * sc.x + sh.x, 0.f);
    float x1 = fmaxf(bfhi(xu) * sc.y + sh.y, 0.f);
    float4 w4 = *(const float4*)&W3[lane * 4];
    float p0 = x0 * w4.x + x1 * w4.z;
    float p1 = x0 * w4.y + x1 * w4.w;
#pragma unroll
    for (int off = 32; off; off >>= 1) {
        p0 += __shfl_xor(p0, off);
        p1 += __shfl_xor(p1, off);
    }
    if (lane == 0) *(float2*)&Z[wid * 2] = make_float2(p0, p1);
}

// ---- layer-3 CSR gather + softmax ----
__global__ void k_l3(const float* __restrict__ Z, const int* __restrict__ rp,
                     const uint2* __restrict__ ec, const float* __restrict__ di,
                     const float* __restrict__ b3, float* __restrict__ out) {
    int n = blockIdx.x * blockDim.x + threadIdx.x;
    if (n >= NN) return;
    int beg = rp[n], end = rp[n + 1];
    float dv = di[n];
    float2 z = *(const float2*)&Z[n * 2];
    float a0 = z.x * dv + b3[0];
    float a1 = z.y * dv + b3[1];
    for (int i = beg; i < end; ++i) {
        uint2 e0 = ec[i];
        float c = __uint_as_float(e0.y);
        float2 v = *(const float2*)&Z[e0.x * 2];
        a0 += v.x * c;
        a1 += v.y * c;
    }
    float m = fmaxf(a0, a1);
    float e0 = __expf(a0 - m), e1 = __expf(a1 - m);
    float inv = 1.0f / (e0 + e1);
    *(float2*)&out[n * 2] = make_float2(e0 * inv, e1 * inv);
}

extern "C" void kernel_launch(void* const* d_in, const int* in_sizes, int n_in,
                              void* d_out, int out_size, void* d_ws, size_t ws_size,
                              hipStream_t stream) {
    const float* x  = (const float*)d_in[0];
    const float* W1 = (const float*)d_in[1];
    const float* b1 = (const float*)d_in[2];
    const float* g1 = (const float*)d_in[3];
    const float* be1= (const float*)d_in[4];
    const float* W2 = (const float*)d_in[5];
    const float* b2 = (const float*)d_in[6];
    const float* g2 = (const float*)d_in[7];
    const float* be2= (const float*)d_in[8];
    const float* W3 = (const float*)d_in[9];
    const float* b3 = (const float*)d_in[10];
    const int*   ei = (const int*)d_in[11];
    const int* srcp = ei;
    const int* dstp = ei + NE;
    float* out = (float*)d_out;

    char* wsp = (char*)d_ws;
    auto alloc = [&](size_t bytes) {
        char* p = wsp;
        wsp += (bytes + 255) & ~(size_t)255;
        return p;
    };
    ushort* Hb   = (ushort*)alloc((size_t)NH * 2);
    uint*   AGGb = (uint*)alloc((size_t)NN * 64 * 4);
    ushort* Wt   = (ushort*)alloc(16384 * 2);
    float*  Z    = (float*)alloc((size_t)2 * NN * 4);
    float*  dis  = (float*)alloc((size_t)NN * 4);
    float*  di   = (float*)alloc((size_t)NN * 4);
    float*  partial = (float*)alloc((size_t)GB * 256 * 4);
    float*  par  = (float*)alloc(512 * 4);
    uint2*  ec   = (uint2*)alloc((size_t)NE * 8);
    uint*   ebuf = (uint*)alloc((size_t)NB * CAP * 4);
    int*    gcur = (int*)alloc(NB * 4);
    int*    rp   = (int*)alloc((size_t)(NN + 1) * 4);
    float*  par1 = par;
    float*  par2 = par + 256;

    const int B = 256;
    const int gN  = (NN + B - 1) / B;
    const int gMM = (NN + 127) / 128;
    const int gW  = (int)(((long long)NN * 64 + B - 1) / B);
    const int gPT = (NE + EPB - 1) / EPB;  // 196

    // ---- CSR build (bucketed) ----
    hipMemsetAsync(gcur, 0, NB * sizeof(int), stream);
    k_part<<<gPT, B, 0, stream>>>(srcp, dstp, gcur, ebuf);
    k_c1<<<NB, B, 0, stream>>>(ebuf, gcur, dis, di, rp);
    k_c2<<<NB, B, 0, stream>>>(ebuf, gcur, rp, dis, ec);

    // ---- layer 1 (x f32 converted in-register) ----
    k_cvt_w<<<64, 256, 0, stream>>>(W1, Wt);
    k_mm_mfma<2><<<gMM, B, 0, stream>>>(x, Wt, nullptr, Hb, NN);
    k_gather_b<<<GB, B, 0, stream>>>(Hb, rp, ec, di, b1, AGGb, partial);
    k_red<<<1, 256, 0, stream>>>(partial, g1, be1, par1);

    // ---- layer 2 (BN1+ReLU fused into A-load) ----
    k_cvt_w<<<64, 256, 0, stream>>>(W2, Wt);
    k_mm_mfma<1><<<gMM, B, 0, stream>>>(AGGb, Wt, par1, Hb, NN);
    k_gather_b<<<GB, B, 0, stream>>>(Hb, rp, ec, di, b2, AGGb, partial);
    k_red<<<1, 256, 0, stream>>>(partial, g2, be2, par2);

    // ---- layer 3 (BN2+ReLU fused) + softmax ----
    k_mm2<<<gW, B, 0, stream>>>(AGGb, W3, par2, Z);
    k_l3<<<gN, B, 0, stream>>>(Z, rp, ec, di, b3, out);
}

// Round 14
// 384.723 us; speedup vs baseline: 1.2188x; 1.2188x over previous
//
#include <hip/hip_runtime.h>

#define NN 100000
#define NE 1600000
#define DF 128
#define NH (NN * DF)
#define EPS 1e-5f
#define NB 196        // buckets of 512 dst nodes
#define CAP 10240     // per-bucket edge capacity
#define EPB 8192      // edges per k_part block
#define GB 2048       // gather blocks: 8 blocks/CU x 256 CU

typedef unsigned int uint;
typedef unsigned short ushort;
typedef __attribute__((ext_vector_type(8))) short bf16x8;
typedef __attribute__((ext_vector_type(4))) float f32x4;

__device__ __forceinline__ ushort f2bf(float f) {
    uint u = __float_as_uint(f);
    u += 0x7fffu + ((u >> 16) & 1u);
    return (ushort)(u >> 16);
}
__device__ __forceinline__ float bflo(uint u) { return __uint_as_float(u << 16); }
__device__ __forceinline__ float bfhi(uint u) { return __uint_as_float(u & 0xffff0000u); }

// ---- pass B: partition edges into 196 bucket lists, packed (src | dloc<<17) ----
__launch_bounds__(256)
__global__ void k_part(const int* __restrict__ src, const int* __restrict__ dst,
                       int* __restrict__ gcur, uint* __restrict__ ebuf) {
    __shared__ int cnt[NB], base[NB];
    int t = threadIdx.x;
    if (t < NB) cnt[t] = 0;
    __syncthreads();
    int e0 = blockIdx.x * EPB;
#pragma unroll
    for (int i = 0; i < EPB / 256; ++i) {
        int e = e0 + i * 256 + t;
        if (e < NE) atomicAdd(&cnt[dst[e] >> 9], 1);
    }
    __syncthreads();
    if (t < NB) {
        base[t] = atomicAdd(&gcur[t], cnt[t]);
        cnt[t] = 0;
    }
    __syncthreads();
#pragma unroll
    for (int i = 0; i < EPB / 256; ++i) {
        int e = e0 + i * 256 + t;
        if (e < NE) {
            int d = dst[e];
            int b = d >> 9;
            int off = atomicAdd(&cnt[b], 1);
            ebuf[b * CAP + base[b] + off] = (uint)src[e] | ((uint)(d & 511) << 17);
        }
    }
}

// ---- pass C1: per bucket, per-node degree -> dis/di/rp (bucket prefix in-block) ----
__launch_bounds__(256)
__global__ void k_c1(const uint* __restrict__ ebuf, const int* __restrict__ gcur,
                     float* __restrict__ dis, float* __restrict__ di,
                     int* __restrict__ rp) {
    __shared__ int ncnt[512];
    __shared__ int ssum[256];
    __shared__ int bsh[256];
    __shared__ int sbase;
    int b = blockIdx.x, t = threadIdx.x;
    bsh[t] = (t < b && t < NB) ? gcur[t] : 0;
    ncnt[t] = 0;
    ncnt[t + 256] = 0;
    __syncthreads();
    for (int off = 128; off; off >>= 1) {
        if (t < off) bsh[t] += bsh[t + off];
        __syncthreads();
    }
    if (t == 0) sbase = bsh[0];
    __syncthreads();
    int base = sbase;

    int ne = gcur[b];
    const uint* eb = ebuf + (size_t)b * CAP;
    for (int e = t; e < ne; e += 256) atomicAdd(&ncnt[eb[e] >> 17], 1);
    __syncthreads();
    int a0 = ncnt[t * 2], a1 = ncnt[t * 2 + 1];
    int ps = a0 + a1;
    ssum[t] = ps;
    __syncthreads();
    for (int off = 1; off < 256; off <<= 1) {
        int x = (t >= off) ? ssum[t - off] : 0;
        __syncthreads();
        ssum[t] += x;
        __syncthreads();
    }
    int excl = ssum[t] - ps;
    int g0 = b * 512 + t * 2;
    if (g0 < NN) {
        rp[g0] = base + excl;
        float d = (float)a0 + 1.0f;
        dis[g0] = rsqrtf(d);
        di[g0] = 1.0f / d;
    }
    if (g0 + 1 < NN) {
        rp[g0 + 1] = base + excl + a0;
        float d = (float)a1 + 1.0f;
        dis[g0 + 1] = rsqrtf(d);
        di[g0 + 1] = 1.0f / d;
    }
    if (b == NB - 1 && t == 0) rp[NN] = NE;
}

// ---- pass C2: per bucket, place (src, coef) into CSR window (L2-combined) ----
__launch_bounds__(256)
__global__ void k_c2(const uint* __restrict__ ebuf, const int* __restrict__ gcur,
                     const int* __restrict__ rp, const float* __restrict__ dis,
                     uint2* __restrict__ ec) {
    __shared__ int cur[512];
    __shared__ float dl[512];
    int b = blockIdx.x, t = threadIdx.x;
#pragma unroll
    for (int i = 0; i < 2; ++i) {
        int g = b * 512 + t + i * 256;
        if (g < NN) {
            cur[t + i * 256] = rp[g];
            dl[t + i * 256] = dis[g];
        }
    }
    __syncthreads();
    int ne = gcur[b];
    const uint* eb = ebuf + (size_t)b * CAP;
    for (int e = t; e < ne; e += 256) {
        uint u = eb[e];
        int s = u & 0x1FFFF;
        int dloc = u >> 17;
        int pos = atomicAdd(&cur[dloc], 1);
        ec[pos] = make_uint2((uint)s, __float_as_uint(dis[s] * dl[dloc]));
    }
}

// ---- convert W -> bf16 transposed+swizzled ----
__global__ void k_cvt_w(const float* __restrict__ W, ushort* __restrict__ Wt) {
    int id = blockIdx.x * blockDim.x + threadIdx.x;
    int n = id & 127, k = id >> 7;
    ushort b = f2bf(W[id]);
    int byte = n * 256 + (((k >> 3) ^ (n & 7)) << 4) + ((k & 7) << 1);
    *(ushort*)((char*)Wt + byte) = b;
}

// ---- MFMA matmul; MODE 0: bf16 A, 1: bf16 A + BN/ReLU, 2: f32 A (converts) ----
template <int MODE>
__launch_bounds__(256, 2)
__global__ void k_mm_mfma(const void* __restrict__ Xv, const ushort* __restrict__ Wt,
                          const float* __restrict__ par, ushort* __restrict__ Y,
                          int nrows) {
    __shared__ uint4 ws4[2048];  // 32 KB
    char* ws = (char*)ws4;
    const int tid = threadIdx.x;
    const int wv = tid >> 6, l = tid & 63;
    const int l15 = l & 15, l4 = l >> 4;
    const int row_base = blockIdx.x * 128 + wv * 32;
    const bool act = row_base < nrows;

    bf16x8 a[2][4];
    if (act) {
#pragma unroll
        for (int mt = 0; mt < 2; ++mt)
#pragma unroll
            for (int ks = 0; ks < 4; ++ks) {
                int r = row_base + mt * 16 + l15;
                if (MODE == 2) {
                    const float* Xf = (const float*)Xv;
                    float4 f0 = *(const float4*)&Xf[(size_t)r * 128 + ks * 32 + l4 * 8];
                    float4 f1 = *(const float4*)&Xf[(size_t)r * 128 + ks * 32 + l4 * 8 + 4];
                    bf16x8 v;
                    v[0] = (short)f2bf(f0.x); v[1] = (short)f2bf(f0.y);
                    v[2] = (short)f2bf(f0.z); v[3] = (short)f2bf(f0.w);
                    v[4] = (short)f2bf(f1.x); v[5] = (short)f2bf(f1.y);
                    v[6] = (short)f2bf(f1.z); v[7] = (short)f2bf(f1.w);
                    a[mt][ks] = v;
                } else {
                    const ushort* Xb = (const ushort*)Xv;
                    a[mt][ks] = *(const bf16x8*)&Xb[(size_t)r * 128 + ks * 32 + l4 * 8];
                }
            }
        if (MODE == 1) {
#pragma unroll
            for (int ks = 0; ks < 4; ++ks) {
                int k0 = ks * 32 + l4 * 8;
                float4 sa = *(const float4*)&par[k0];
                float4 sb = *(const float4*)&par[k0 + 4];
                float4 ha = *(const float4*)&par[128 + k0];
                float4 hb = *(const float4*)&par[128 + k0 + 4];
                float sc[8] = {sa.x, sa.y, sa.z, sa.w, sb.x, sb.y, sb.z, sb.w};
                float sh[8] = {ha.x, ha.y, ha.z, ha.w, hb.x, hb.y, hb.z, hb.w};
#pragma unroll
                for (int mt = 0; mt < 2; ++mt)
#pragma unroll
                    for (int j = 0; j < 8; ++j) {
                        float f = __uint_as_float(((uint)(ushort)a[mt][ks][j]) << 16);
                        f = fmaxf(f * sc[j] + sh[j], 0.0f);
                        a[mt][ks][j] = (short)f2bf(f);
                    }
            }
        }
    }
    const uint4* Wg = (const uint4*)Wt;
#pragma unroll
    for (int i = 0; i < 8; ++i) ws4[tid + i * 256] = Wg[tid + i * 256];
    __syncthreads();
    if (!act) return;

    f32x4 acc[2][8];
#pragma unroll
    for (int mt = 0; mt < 2; ++mt)
#pragma unroll
        for (int nt = 0; nt < 8; ++nt) acc[mt][nt] = (f32x4){0.f, 0.f, 0.f, 0.f};

#pragma unroll
    for (int ks = 0; ks < 4; ++ks) {
        bf16x8 b[8];
#pragma unroll
        for (int nt = 0; nt < 8; ++nt) {
            int n = nt * 16 + l15;
            int chunk = (ks * 4 + l4) ^ (n & 7);
            b[nt] = *(const bf16x8*)(ws + n * 256 + chunk * 16);
        }
#pragma unroll
        for (int nt = 0; nt < 8; ++nt) {
            acc[0][nt] = __builtin_amdgcn_mfma_f32_16x16x32_bf16(a[0][ks], b[nt], acc[0][nt], 0, 0, 0);
            acc[1][nt] = __builtin_amdgcn_mfma_f32_16x16x32_bf16(a[1][ks], b[nt], acc[1][nt], 0, 0, 0);
        }
    }
#pragma unroll
    for (int mt = 0; mt < 2; ++mt)
#pragma unroll
        for (int nt = 0; nt < 8; ++nt)
#pragma unroll
            for (int r = 0; r < 4; ++r) {
                int ro = row_base + mt * 16 + l4 * 4 + r;
                Y[(size_t)ro * 128 + nt * 16 + l15] = f2bf(acc[mt][nt][r]);
            }
}

// ---- CSR gather (bf16) + fused BN stats; grid-stride, 16/8/4-deep unroll ----
__launch_bounds__(256, 8)
__global__ void k_gather_b(const ushort* __restrict__ H, const int* __restrict__ rp,
                           const uint2* __restrict__ ec, const float* __restrict__ di,
                           const float* __restrict__ b, uint* __restrict__ outb,
                           float* __restrict__ partial) {
    int wv = threadIdx.x >> 6, lane = threadIdx.x & 63;
    const uint* H32 = (const uint*)H;
    float2 bb = *(const float2*)&b[lane * 2];
    float s0 = 0.f, s1 = 0.f, q0 = 0.f, q1 = 0.f;

    for (int wid = blockIdx.x * 4 + wv; wid < NN; wid += GB * 4) {
        int beg = rp[wid], end = rp[wid + 1];
        float dv = di[wid];
        uint hu = H32[(size_t)wid * 64 + lane];
        float ax = bflo(hu) * dv + bb.x;
        float ay = bfhi(hu) * dv + bb.y;
        int i = beg;
        for (; i + 15 < end; i += 16) {
            uint2 e[16];
            uint u[16];
#pragma unroll
            for (int j = 0; j < 16; ++j) e[j] = ec[i + j];
#pragma unroll
            for (int j = 0; j < 16; ++j) u[j] = H32[(size_t)e[j].x * 64 + lane];
#pragma unroll
            for (int j = 0; j < 16; ++j) {
                float c = __uint_as_float(e[j].y);
                ax += bflo(u[j]) * c;
                ay += bfhi(u[j]) * c;
            }
        }
        for (; i + 7 < end; i += 8) {
            uint2 e[8];
            uint u[8];
#pragma unroll
            for (int j = 0; j < 8; ++j) e[j] = ec[i + j];
#pragma unroll
            for (int j = 0; j < 8; ++j) u[j] = H32[(size_t)e[j].x * 64 + lane];
#pragma unroll
            for (int j = 0; j < 8; ++j) {
                float c = __uint_as_float(e[j].y);
                ax += bflo(u[j]) * c;
                ay += bfhi(u[j]) * c;
            }
        }
        for (; i + 3 < end; i += 4) {
            uint2 e[4];
            uint u[4];
#pragma unroll
            for (int j = 0; j < 4; ++j) e[j] = ec[i + j];
#pragma unroll
            for (int j = 0; j < 4; ++j) u[j] = H32[(size_t)e[j].x * 64 + lane];
#pragma unroll
            for (int j = 0; j < 4; ++j) {
                float c = __uint_as_float(e[j].y);
                ax += bflo(u[j]) * c;
                ay += bfhi(u[j]) * c;
            }
        }
        for (; i < end; ++i) {
            uint2 e0 = ec[i];
            uint u = H32[(size_t)e0.x * 64 + lane];
            float c = __uint_as_float(e0.y);
            ax += bflo(u) * c;
            ay += bfhi(u) * c;
        }
        outb[(size_t)wid * 64 + lane] = (uint)f2bf(ax) | ((uint)f2bf(ay) << 16);
        s0 += ax; q0 += ax * ax;
        s1 += ay; q1 += ay * ay;
    }

    __shared__ float Ls[4][128], Lq[4][128];
    Ls[wv][2 * lane] = s0;
    Ls[wv][2 * lane + 1] = s1;
    Lq[wv][2 * lane] = q0;
    Lq[wv][2 * lane + 1] = q1;
    __syncthreads();
    int t = threadIdx.x;
    if (t < 128)
        partial[(size_t)blockIdx.x * 256 + t] = Ls[0][t] + Ls[1][t] + Ls[2][t] + Ls[3][t];
    else {
        int c = t - 128;
        partial[(size_t)blockIdx.x * 256 + t] = Lq[0][c] + Lq[1][c] + Lq[2][c] + Lq[3][c];
    }
}

// ---- reduce partials, stage 1: 128 blocks x 16 rows -> p2[128][256] ----
__global__ void k_red1(const float* __restrict__ partial, float* __restrict__ p2) {
    int j = blockIdx.x, t = threadIdx.x;
    float acc = 0.f;
#pragma unroll
    for (int r = 0; r < GB / 128; ++r)
        acc += partial[(size_t)(j * (GB / 128) + r) * 256 + t];
    p2[(size_t)j * 256 + t] = acc;
}

// ---- reduce partials, stage 2: sum 128 rows + BN params ----
__global__ void k_red2(const float* __restrict__ p2, const float* __restrict__ g,
                       const float* __restrict__ be, float* __restrict__ par) {
    int c = threadIdx.x;  // 0..255
    float acc = 0.f;
#pragma unroll 8
    for (int b = 0; b < 128; ++b) acc += p2[b * 256 + c];
    __shared__ float sh[256];
    sh[c] = acc;
    __syncthreads();
    if (c < 128) {
        float mu = sh[c] * (1.0f / NN);
        float var = sh[c + 128] * (1.0f / NN) - mu * mu;
        float inv = rsqrtf(var + EPS);
        float scv = inv * g[c];
        par[c] = scv;
        par[128 + c] = be[c] - mu * scv;
    }
}

// ---- layer-3: affine+relu on bf16 agg, dot W3; one wave per node ----
__global__ void k_mm2(const uint* __restrict__ X, const float* __restrict__ W3,
                      const float* __restrict__ par, float* __restrict__ Z) {
    int wid = (int)(((long long)blockIdx.x * blockDim.x + threadIdx.x) >> 6);
    int lane = threadIdx.x & 63;
    if (wid >= NN) return;
    uint xu = X[(size_t)wid * 64 + lane];
    float2 sc = *(const float2*)&par[2 * lane];
    float2 sh = *(const float2*)&par[128 + 2 * lane];
    float x0 = fmaxf(bflo(xu) * sc.x + sh.x, 0.f);
    float x1 = fmaxf(bfhi(xu) * sc.y + sh.y, 0.f);
    float4 w4 = *(const float4*)&W3[lane * 4];
    float p0 = x0 * w4.x + x1 * w4.z;
    float p1 = x0 * w4.y + x1 * w4.w;
#pragma unroll
    for (int off = 32; off; off >>= 1) {
        p0 += __shfl_xor(p0, off);
        p1 += __shfl_xor(p1, off);
    }
    if (lane == 0) *(float2*)&Z[wid * 2] = make_float2(p0, p1);
}

// ---- layer-3 CSR gather + softmax ----
__global__ void k_l3(const float* __restrict__ Z, const int* __restrict__ rp,
                     const uint2* __restrict__ ec, const float* __restrict__ di,
                     const float* __restrict__ b3, float* __restrict__ out) {
    int n = blockIdx.x * blockDim.x + threadIdx.x;
    if (n >= NN) return;
    int beg = rp[n], end = rp[n + 1];
    float dv = di[n];
    float2 z = *(const float2*)&Z[n * 2];
    float a0 = z.x * dv + b3[0];
    float a1 = z.y * dv + b3[1];
    for (int i = beg; i < end; ++i) {
        uint2 e0 = ec[i];
        float c = __uint_as_float(e0.y);
        float2 v = *(const float2*)&Z[e0.x * 2];
        a0 += v.x * c;
        a1 += v.y * c;
    }
    float m = fmaxf(a0, a1);
    float e0 = __expf(a0 - m), e1 = __expf(a1 - m);
    float inv = 1.0f / (e0 + e1);
    *(float2*)&out[n * 2] = make_float2(e0 * inv, e1 * inv);
}

extern "C" void kernel_launch(void* const* d_in, const int* in_sizes, int n_in,
                              void* d_out, int out_size, void* d_ws, size_t ws_size,
                              hipStream_t stream) {
    const float* x  = (const float*)d_in[0];
    const float* W1 = (const float*)d_in[1];
    const float* b1 = (const float*)d_in[2];
    const float* g1 = (const float*)d_in[3];
    const float* be1= (const float*)d_in[4];
    const float* W2 = (const float*)d_in[5];
    const float* b2 = (const float*)d_in[6];
    const float* g2 = (const float*)d_in[7];
    const float* be2= (const float*)d_in[8];
    const float* W3 = (const float*)d_in[9];
    const float* b3 = (const float*)d_in[10];
    const int*   ei = (const int*)d_in[11];
    const int* srcp = ei;
    const int* dstp = ei + NE;
    float* out = (float*)d_out;

    char* wsp = (char*)d_ws;
    auto alloc = [&](size_t bytes) {
        char* p = wsp;
        wsp += (bytes + 255) & ~(size_t)255;
        return p;
    };
    ushort* Hb   = (ushort*)alloc((size_t)NH * 2);
    uint*   AGGb = (uint*)alloc((size_t)NN * 64 * 4);
    ushort* Wt   = (ushort*)alloc(16384 * 2);
    float*  Z    = (float*)alloc((size_t)2 * NN * 4);
    float*  dis  = (float*)alloc((size_t)NN * 4);
    float*  di   = (float*)alloc((size_t)NN * 4);
    float*  partial = (float*)alloc((size_t)GB * 256 * 4);
    float*  p2   = (float*)alloc((size_t)128 * 256 * 4);
    float*  par  = (float*)alloc(512 * 4);
    uint2*  ec   = (uint2*)alloc((size_t)NE * 8);
    uint*   ebuf = (uint*)alloc((size_t)NB * CAP * 4);
    int*    gcur = (int*)alloc(NB * 4);
    int*    rp   = (int*)alloc((size_t)(NN + 1) * 4);
    float*  par1 = par;
    float*  par2 = par + 256;

    const int B = 256;
    const int gN  = (NN + B - 1) / B;
    const int gMM = (NN + 127) / 128;
    const int gW  = (int)(((long long)NN * 64 + B - 1) / B);
    const int gPT = (NE + EPB - 1) / EPB;  // 196

    // ---- CSR build (bucketed) ----
    hipMemsetAsync(gcur, 0, NB * sizeof(int), stream);
    k_part<<<gPT, B, 0, stream>>>(srcp, dstp, gcur, ebuf);
    k_c1<<<NB, B, 0, stream>>>(ebuf, gcur, dis, di, rp);
    k_c2<<<NB, B, 0, stream>>>(ebuf, gcur, rp, dis, ec);

    // ---- layer 1 (x f32 converted in-register) ----
    k_cvt_w<<<64, 256, 0, stream>>>(W1, Wt);
    k_mm_mfma<2><<<gMM, B, 0, stream>>>(x, Wt, nullptr, Hb, NN);
    k_gather_b<<<GB, B, 0, stream>>>(Hb, rp, ec, di, b1, AGGb, partial);
    k_red1<<<128, 256, 0, stream>>>(partial, p2);
    k_red2<<<1, 256, 0, stream>>>(p2, g1, be1, par1);

    // ---- layer 2 (BN1+ReLU fused into A-load) ----
    k_cvt_w<<<64, 256, 0, stream>>>(W2, Wt);
    k_mm_mfma<1><<<gMM, B, 0, stream>>>(AGGb, Wt, par1, Hb, NN);
    k_gather_b<<<GB, B, 0, stream>>>(Hb, rp, ec, di, b2, AGGb, partial);
    k_red1<<<128, 256, 0, stream>>>(partial, p2);
    k_red2<<<1, 256, 0, stream>>>(p2, g2, be2, par2);

    // ---- layer 3 (BN2+ReLU fused) + softmax ----
    k_mm2<<<gW, B, 0, stream>>>(AGGb, W3, par2, Z);
    k_l3<<<gN, B, 0, stream>>>(Z, rp, ec, di, b3, out);
}